// Round 12
// baseline (142.933 us; speedup 1.0000x reference)
//
#include <hip/hip_runtime.h>
#include <math.h>

#define NSTEPS 216
#define SEG 27                 // steps per segment (= per thread)
#define CREG 18                // c[0..CREG) in VGPRs, rest in LDS
#define NSEG 8                 // segments (waves) per row
#define ROWS 64                // rows per block (= lanes per wave)
#define THREADS (ROWS * NSEG)  // 512
#define CSTR 55                // LDS staging stride, coprime with 32 banks
#define PSTR 17                // param LDS stride, coprime with 32 banks

#if __has_builtin(__builtin_amdgcn_exp2f)
#define EXP2F(x) __builtin_amdgcn_exp2f(x)
#else
#define EXP2F(x) exp2f(x)
#endif

// Fallback table storage if d_ws is unavailable (tbl[0..216)=th, [216..432)=H*z0)
__device__ float g_tbl[2 * NSTEPS];

__global__ void traj_kernel() {   // fallback only
    __shared__ float xs[NSTEPS], ys[NSTEPS];
    const int t = threadIdx.x;
    if (t == 0) {
        float x = (float)(-0.417750770388669);
        float y = (float)(-0.9085616622823985);
        const float W = (float)(2.0 * M_PI);
        const float H = (float)(1.0 / 216.0);
        for (int n = 0; n < NSTEPS; ++n) {
            xs[n] = x; ys[n] = y;
            float alpha = 1.0f - sqrtf(x * x + y * y);
            float fx = alpha * x - W * y;
            float fy = alpha * y + W * x;
            x = x + H * fx;
            y = y + H * fy;
        }
    }
    __syncthreads();
    if (t < NSTEPS) {
        g_tbl[t] = atan2f(ys[t], xs[t]);
        float tf = (float)t / 216.0f;
        g_tbl[NSTEPS + t] = (float)(1.0 / 216.0) * (0.005f * sinf(1.5707964f * tf));
    }
}

// z_n = K*z_{n-1} + c_t is AFFINE in z with z-independent forcing c_t.
// => time-parallel: 8 threads/row each own 27 steps, compute c_t ONCE,
// combine segment affine maps (z -> K^27 z + S), then replay with cheap
// FMAs. c[] split 18-in-VGPR + 9-in-LDS under (512,8).
// R12 = R11 resubmitted VERBATIM (R11 failed on container infra, no data
// — same as R3/R4 precedent). Change vs R8 (best, 134.8us): SHARED PARAM
// PREP — the 15 param loads + 5 divides + 5 log2 were done 8x-redundantly
// per row (once per segment thread). Now: coalesced 960-float block load
// into LDS [64][17] (stride 17 coprime 32 -> conflict-free), 320 workers
// derive (la2,cj2) in place once, all threads read finished constants.
// Identical float expressions -> bit-identical output.
// Lessons: R5 hand-asm VOP3P corrupts; R6 in-block tables wreck regalloc;
// R7 wave-per-row adds issue; R9 write-vectorization null; R10 f2-packing
// null; occupancy NOT the lever (R4 16% == R7 77%).
__global__ __launch_bounds__(THREADS, 8) void euler_kernel(const float* __restrict__ prm,
                                                           const float* __restrict__ v0,
                                                           float* __restrict__ out,
                                                           const float* __restrict__ tbl) {
    __shared__ float th_s[NSTEPS];
    __shared__ float hz0_s[NSTEPS];
    __shared__ float Sz[NSEG][ROWS];      // segment offsets S
    __shared__ float Smn[NSEG][ROWS];     // per-segment min
    __shared__ float Smx[NSEG][ROWS];     // per-segment max
    __shared__ float st_s[ROWS * CSTR];   // 64 rows x 54 scaled outputs, stride 55
    __shared__ float c_lds[SEG - CREG][THREADS];  // 9 x 512, lane-stride: conflict-free
    __shared__ float pp[ROWS][PSTR];      // per-row params: raw then derived in place

    const int tid = threadIdx.x;
    const int row = tid & (ROWS - 1);     // lane within wave
    const int seg = tid >> 6;             // wave id = segment id (wave-uniform)

    if (tid < NSTEPS) {
        th_s[tid] = tbl[tid];
        hz0_s[tid] = tbl[NSTEPS + tid];
    }

    // ---- cooperative param load: 64 rows x 15 floats, coalesced ----
    {
        const float* pblk = prm + (size_t)blockIdx.x * (ROWS * 15);
#pragma unroll
        for (int k = 0; k < 2; ++k) {
            int i = tid + k * THREADS;
            if (i < ROWS * 15) {
                int r = i / 15;
                pp[r][i - r * 15] = pblk[i];
            }
        }
    }
    __syncthreads();                      // raw params + (tables in flight)

    // ---- derive (la2, cj2) once per (row, j): 320 workers ----
    // gaussian_j(d) = a*d*exp(-d^2/(2b^2)) = d * exp2(d^2*cj2 + la2),
    // log2e folded so the hot loop is pure v_exp_f32.
    const float LOG2E = 1.4426950408889634f;
    if (tid < ROWS * 5) {
        int r = tid / 5, j = tid - 5 * r;
        float a  = pp[r][3 * j + 0];
        float bb = pp[r][3 * j + 1];
        pp[r][3 * j + 0] = __log2f(a);
        pp[r][3 * j + 1] = -LOG2E / (2.0f * bb * bb);
    }

    const int b = blockIdx.x * ROWS + row;
    const float zinit = v0[b];
    const float H = (float)(1.0 / 216.0);
    const float K = 1.0f - H;
    // A = K^27 by squaring (uniform): 16+8+2+1
    const float K2 = K * K, K8 = K2 * K2 * K2 * K2;
    const float A = K8 * K8 * K8 * K2 * K;

    __syncthreads();                      // derived + tables ready

    // ---- fetch finished constants (stride-17 LDS: conflict-free) ----
    float tj[5], cj2[5], la2[5];
#pragma unroll
    for (int j = 0; j < 5; ++j) {
        la2[j] = pp[row][3 * j + 0];
        cj2[j] = pp[row][3 * j + 1];
        tj[j]  = pp[row][3 * j + 2];
    }

    // ---- heavy pass (ONCE): forcing terms c_t for my 27 steps ----
    const int t0 = seg * SEG;
    float c[CREG];
    float S = 0.0f;                        // segment map applied to z=0
#pragma unroll
    for (int i = 0; i < SEG; ++i) {
        float th = th_s[t0 + i];
        float G = 0.0f;
#pragma unroll
        for (int j = 0; j < 5; ++j) {
            float d = th - tj[j];
            G = fmaf(d, EXP2F(fmaf(d * d, cj2[j], la2[j])), G);
        }
        float ci = fmaf(-H, G, hz0_s[t0 + i]);
        if (i < CREG) c[i] = ci;           // compile-time split (full unroll)
        else          c_lds[i - CREG][tid] = ci;
        S = fmaf(S, K, ci);
    }
    Sz[seg][row] = S;
    __syncthreads();

    // ---- combine: z at my segment start (seg is wave-uniform -> no div) ----
    float z = zinit;
#pragma unroll
    for (int j = 0; j < NSEG - 1; ++j)
        if (j < seg) z = fmaf(z, A, Sz[j][row]);

    // ---- replay: cheap FMAs, overwrite storage with z_t, track min/max ----
    float zmn = 3.4e38f, zmx = -3.4e38f;
#pragma unroll
    for (int i = 0; i < SEG; ++i) {
        float ci = (i < CREG) ? c[i] : c_lds[i - CREG][tid];
        z = fmaf(z, K, ci);
        if (i < CREG) c[i] = z;
        else          c_lds[i - CREG][tid] = z;
        zmn = fminf(zmn, z);
        zmx = fmaxf(zmx, z);
    }
    Smn[seg][row] = zmn;
    Smx[seg][row] = zmx;
    __syncthreads();
#pragma unroll
    for (int j = 0; j < NSEG; ++j) {
        zmn = fminf(zmn, Smn[j][row]);
        zmx = fmaxf(zmx, Smx[j][row]);
    }
    const float s = 0.042557f / (zmx - zmn);
    const float o = fmaf(-zmn, s, -0.01563f);

    // ---- staged coalesced write: chunk = 2 segments = 54 steps ----
    float* outB = out + (size_t)blockIdx.x * (ROWS * NSTEPS);
#pragma unroll
    for (int ch = 0; ch < NSEG / 2; ++ch) {
        if ((seg >> 1) == ch) {            // wave-uniform
            const int base = (seg & 1) * SEG;
#pragma unroll
            for (int i = 0; i < SEG; ++i) {
                float zi = (i < CREG) ? c[i] : c_lds[i - CREG][tid];
                st_s[row * CSTR + base + i] = fmaf(zi, s, o);
            }
        }
        __syncthreads();
        // 64*54 = 3456 staged elements -> 512 threads x 6.75
#pragma unroll
        for (int k = 0; k < 6; ++k) {
            unsigned idx = (unsigned)tid + THREADS * k;
            unsigned r = idx / 54u;
            unsigned tt = idx - r * 54u;
            outB[r * NSTEPS + ch * 54 + tt] = st_s[r * CSTR + tt];
        }
        if (tid < 3456 - 6 * THREADS) {
            unsigned idx = (unsigned)tid + THREADS * 6;
            unsigned r = idx / 54u;
            unsigned tt = idx - r * 54u;
            outB[r * NSTEPS + ch * 54 + tt] = st_s[r * CSTR + tt];
        }
        __syncthreads();
    }
}

// ---- host-side table precompute (input-independent constants) ----
static float h_tbl[2 * NSTEPS];
static bool h_tbl_init = false;

static void init_tbl() {
    float xs[NSTEPS], ys[NSTEPS];
    float x = (float)(-0.417750770388669);
    float y = (float)(-0.9085616622823985);
    const float W = (float)(2.0 * M_PI);
    const float Hh = (float)(1.0 / 216.0);
    for (int n = 0; n < NSTEPS; ++n) {
        xs[n] = x; ys[n] = y;
        float alpha = 1.0f - sqrtf(x * x + y * y);
        float fx = alpha * x - W * y;
        float fy = alpha * y + W * x;
        x = x + Hh * fx;
        y = y + Hh * fy;
    }
    for (int t = 0; t < NSTEPS; ++t) {
        h_tbl[t] = atan2f(ys[t], xs[t]);
        float tf = (float)t / 216.0f;
        h_tbl[NSTEPS + t] = (float)(1.0 / 216.0) * (0.005f * sinf(1.5707964f * tf));
    }
}

extern "C" void kernel_launch(void* const* d_in, const int* in_sizes, int n_in,
                              void* d_out, int out_size, void* d_ws, size_t ws_size,
                              hipStream_t stream) {
    const float* x  = (const float*)d_in[0];
    const float* v0 = (const float*)d_in[1];
    float* out = (float*)d_out;
    const int nb = in_sizes[1];              // 131072 batch rows

    if (!h_tbl_init) { init_tbl(); h_tbl_init = true; }

    const float* tbl;
    if (d_ws != nullptr && ws_size >= sizeof(h_tbl)) {
        // 1.7 KB H2D from persistent static buffer: graph-capture-safe async copy.
        hipMemcpyAsync(d_ws, h_tbl, sizeof(h_tbl), hipMemcpyHostToDevice, stream);
        tbl = (const float*)d_ws;
    } else {
        // fallback: device-side table build (adds a dispatch, ~14us)
        static float* s_gtbl = nullptr;
        if (s_gtbl == nullptr)
            hipGetSymbolAddress((void**)&s_gtbl, HIP_SYMBOL(g_tbl));
        hipLaunchKernelGGL(traj_kernel, dim3(1), dim3(256), 0, stream);
        tbl = (const float*)s_gtbl;
    }

    hipLaunchKernelGGL(euler_kernel, dim3(nb / ROWS), dim3(THREADS), 0, stream,
                       x, v0, out, tbl);
}

// Round 13
// 134.525 us; speedup vs baseline: 1.0625x; 1.0625x over previous
//
#include <hip/hip_runtime.h>
#include <math.h>

#define NSTEPS 216
#define SEG 27                 // steps per segment (= per thread)
#define CREG 18                // c[0..CREG) in VGPRs, rest in LDS
#define NSEG 8                 // segments (waves) per row
#define ROWS 64                // rows per block (= lanes per wave)
#define THREADS (ROWS * NSEG)  // 512
#define CSTR 55                // LDS staging stride, coprime with 32 banks

#if __has_builtin(__builtin_amdgcn_exp2f)
#define EXP2F(x) __builtin_amdgcn_exp2f(x)
#else
#define EXP2F(x) exp2f(x)
#endif

// Fallback table storage if d_ws is unavailable (tbl[0..216)=th, [216..432)=H*z0)
__device__ float g_tbl[2 * NSTEPS];

__global__ void traj_kernel() {   // fallback only
    __shared__ float xs[NSTEPS], ys[NSTEPS];
    const int t = threadIdx.x;
    if (t == 0) {
        float x = (float)(-0.417750770388669);
        float y = (float)(-0.9085616622823985);
        const float W = (float)(2.0 * M_PI);
        const float H = (float)(1.0 / 216.0);
        for (int n = 0; n < NSTEPS; ++n) {
            xs[n] = x; ys[n] = y;
            float alpha = 1.0f - sqrtf(x * x + y * y);
            float fx = alpha * x - W * y;
            float fy = alpha * y + W * x;
            x = x + H * fx;
            y = y + H * fy;
        }
    }
    __syncthreads();
    if (t < NSTEPS) {
        g_tbl[t] = atan2f(ys[t], xs[t]);
        float tf = (float)t / 216.0f;
        g_tbl[NSTEPS + t] = (float)(1.0 / 216.0) * (0.005f * sinf(1.5707964f * tf));
    }
}

// z_n = K*z_{n-1} + c_t is AFFINE in z with z-independent forcing c_t.
// => time-parallel: 8 threads/row each own 27 steps, compute c_t ONCE,
// combine segment affine maps (z -> K^27 z + S), then replay with cheap
// FMAs. c[] split 18-in-VGPR + 9-in-LDS to satisfy (512,8) spill-free.
// R13 = R8 VERBATIM (best measured: 134.8us) — final revert. R12's
// shared-param-prep regressed (−8us: prologue barriers serialize what
// previously hid under staging latency; pp LDS dropped 4->3 blocks/CU).
// Full lesson ledger: R5 hand-asm VOP3P corrupts (op_sel_hi); R6
// in-block table fusion wrecks regalloc; R7 wave-per-row adds issue;
// R9 write-vectorization null; R10 f2-packing null; R12 shared-prep
// negative; occupancy NOT the lever (R4 16% == R7 77%) — euler is at
// its trans-pipe/issue floor; residual total = ~68us harness fill (84%
// HBM peak) + ~20us graph overhead + ~46us euler.
__global__ __launch_bounds__(THREADS, 8) void euler_kernel(const float* __restrict__ prm,
                                                           const float* __restrict__ v0,
                                                           float* __restrict__ out,
                                                           const float* __restrict__ tbl) {
    __shared__ float th_s[NSTEPS];
    __shared__ float hz0_s[NSTEPS];
    __shared__ float Sz[NSEG][ROWS];      // segment offsets S
    __shared__ float Smn[NSEG][ROWS];     // per-segment min
    __shared__ float Smx[NSEG][ROWS];     // per-segment max
    __shared__ float st_s[ROWS * CSTR];   // 64 rows x 54 scaled outputs, stride 55
    __shared__ float c_lds[SEG - CREG][THREADS];  // 9 x 512, lane-stride: conflict-free

    const int tid = threadIdx.x;
    const int row = tid & (ROWS - 1);     // lane within wave
    const int seg = tid >> 6;             // wave id = segment id (wave-uniform)

    if (tid < NSTEPS) {
        th_s[tid] = tbl[tid];
        hz0_s[tid] = tbl[NSTEPS + tid];
    }

    const int b = blockIdx.x * ROWS + row;
    const float* p = prm + (size_t)b * 15;

    // gaussian_j(d) = a*d*exp(-d^2/(2b^2)) = d * exp2(d^2*cj2 + la2)
    // with log2e folded into cj2/la2 so the hot loop is pure v_exp_f32.
    const float LOG2E = 1.4426950408889634f;
    float tj[5], cj2[5], la2[5];
#pragma unroll
    for (int j = 0; j < 5; ++j) {
        float a  = p[3 * j + 0];
        float bb = p[3 * j + 1];
        tj[j] = p[3 * j + 2];
        cj2[j] = -LOG2E / (2.0f * bb * bb);
        la2[j] = __log2f(a);
    }

    const float zinit = v0[b];
    const float H = (float)(1.0 / 216.0);
    const float K = 1.0f - H;
    // A = K^27 by squaring (uniform): 16+8+2+1
    const float K2 = K * K, K8 = K2 * K2 * K2 * K2;
    const float A = K8 * K8 * K8 * K2 * K;

    __syncthreads();

    // ---- heavy pass (ONCE): forcing terms c_t for my 27 steps ----
    const int t0 = seg * SEG;
    float c[CREG];
    float S = 0.0f;                        // segment map applied to z=0
#pragma unroll
    for (int i = 0; i < SEG; ++i) {
        float th = th_s[t0 + i];
        float G = 0.0f;
#pragma unroll
        for (int j = 0; j < 5; ++j) {
            float d = th - tj[j];
            G = fmaf(d, EXP2F(fmaf(d * d, cj2[j], la2[j])), G);
        }
        float ci = fmaf(-H, G, hz0_s[t0 + i]);
        if (i < CREG) c[i] = ci;           // compile-time split (full unroll)
        else          c_lds[i - CREG][tid] = ci;
        S = fmaf(S, K, ci);
    }
    Sz[seg][row] = S;
    __syncthreads();

    // ---- combine: z at my segment start (seg is wave-uniform -> no div) ----
    float z = zinit;
#pragma unroll
    for (int j = 0; j < NSEG - 1; ++j)
        if (j < seg) z = fmaf(z, A, Sz[j][row]);

    // ---- replay: cheap FMAs, overwrite storage with z_t, track min/max ----
    float zmn = 3.4e38f, zmx = -3.4e38f;
#pragma unroll
    for (int i = 0; i < SEG; ++i) {
        float ci = (i < CREG) ? c[i] : c_lds[i - CREG][tid];
        z = fmaf(z, K, ci);
        if (i < CREG) c[i] = z;
        else          c_lds[i - CREG][tid] = z;
        zmn = fminf(zmn, z);
        zmx = fmaxf(zmx, z);
    }
    Smn[seg][row] = zmn;
    Smx[seg][row] = zmx;
    __syncthreads();
#pragma unroll
    for (int j = 0; j < NSEG; ++j) {
        zmn = fminf(zmn, Smn[j][row]);
        zmx = fmaxf(zmx, Smx[j][row]);
    }
    const float s = 0.042557f / (zmx - zmn);
    const float o = fmaf(-zmn, s, -0.01563f);

    // ---- staged coalesced write: chunk = 2 segments = 54 steps ----
    float* outB = out + (size_t)blockIdx.x * (ROWS * NSTEPS);
#pragma unroll
    for (int ch = 0; ch < NSEG / 2; ++ch) {
        if ((seg >> 1) == ch) {            // wave-uniform
            const int base = (seg & 1) * SEG;
#pragma unroll
            for (int i = 0; i < SEG; ++i) {
                float zi = (i < CREG) ? c[i] : c_lds[i - CREG][tid];
                st_s[row * CSTR + base + i] = fmaf(zi, s, o);
            }
        }
        __syncthreads();
        // 64*54 = 3456 staged elements -> 512 threads x 6.75
#pragma unroll
        for (int k = 0; k < 6; ++k) {
            unsigned idx = (unsigned)tid + THREADS * k;
            unsigned r = idx / 54u;
            unsigned tt = idx - r * 54u;
            outB[r * NSTEPS + ch * 54 + tt] = st_s[r * CSTR + tt];
        }
        if (tid < 3456 - 6 * THREADS) {
            unsigned idx = (unsigned)tid + THREADS * 6;
            unsigned r = idx / 54u;
            unsigned tt = idx - r * 54u;
            outB[r * NSTEPS + ch * 54 + tt] = st_s[r * CSTR + tt];
        }
        __syncthreads();
    }
}

// ---- host-side table precompute (input-independent constants) ----
static float h_tbl[2 * NSTEPS];
static bool h_tbl_init = false;

static void init_tbl() {
    float xs[NSTEPS], ys[NSTEPS];
    float x = (float)(-0.417750770388669);
    float y = (float)(-0.9085616622823985);
    const float W = (float)(2.0 * M_PI);
    const float Hh = (float)(1.0 / 216.0);
    for (int n = 0; n < NSTEPS; ++n) {
        xs[n] = x; ys[n] = y;
        float alpha = 1.0f - sqrtf(x * x + y * y);
        float fx = alpha * x - W * y;
        float fy = alpha * y + W * x;
        x = x + Hh * fx;
        y = y + Hh * fy;
    }
    for (int t = 0; t < NSTEPS; ++t) {
        h_tbl[t] = atan2f(ys[t], xs[t]);
        float tf = (float)t / 216.0f;
        h_tbl[NSTEPS + t] = (float)(1.0 / 216.0) * (0.005f * sinf(1.5707964f * tf));
    }
}

extern "C" void kernel_launch(void* const* d_in, const int* in_sizes, int n_in,
                              void* d_out, int out_size, void* d_ws, size_t ws_size,
                              hipStream_t stream) {
    const float* x  = (const float*)d_in[0];
    const float* v0 = (const float*)d_in[1];
    float* out = (float*)d_out;
    const int nb = in_sizes[1];              // 131072 batch rows

    if (!h_tbl_init) { init_tbl(); h_tbl_init = true; }

    const float* tbl;
    if (d_ws != nullptr && ws_size >= sizeof(h_tbl)) {
        // 1.7 KB H2D from persistent static buffer: graph-capture-safe async copy.
        hipMemcpyAsync(d_ws, h_tbl, sizeof(h_tbl), hipMemcpyHostToDevice, stream);
        tbl = (const float*)d_ws;
    } else {
        // fallback: device-side table build (adds a dispatch, ~14us)
        static float* s_gtbl = nullptr;
        if (s_gtbl == nullptr)
            hipGetSymbolAddress((void**)&s_gtbl, HIP_SYMBOL(g_tbl));
        hipLaunchKernelGGL(traj_kernel, dim3(1), dim3(256), 0, stream);
        tbl = (const float*)s_gtbl;
    }

    hipLaunchKernelGGL(euler_kernel, dim3(nb / ROWS), dim3(THREADS), 0, stream,
                       x, v0, out, tbl);
}